// Round 1
// baseline (3013.716 us; speedup 1.0000x reference)
//
#include <hip/hip_runtime.h>
#include <cstdint>
#include <cstddef>

#define B_ 8
#define C_ 512
#define H_ 64
#define W_ 128
#define HW_ 8192
#define K_ 19
#define N_ 8
#define P_ 1024
#define CI_ 256

// ---------------- block reductions (256 threads = 4 waves) ----------------
__device__ __forceinline__ float blockSum256(float v, float* red4) {
#pragma unroll
  for (int o = 32; o > 0; o >>= 1) v += __shfl_down(v, o, 64);
  __syncthreads();
  if ((threadIdx.x & 63) == 0) red4[threadIdx.x >> 6] = v;
  __syncthreads();
  return red4[0] + red4[1] + red4[2] + red4[3];
}

__device__ __forceinline__ float blockMax256(float v, float* red4) {
#pragma unroll
  for (int o = 32; o > 0; o >>= 1) v = fmaxf(v, __shfl_down(v, o, 64));
  __syncthreads();
  if ((threadIdx.x & 63) == 0) red4[threadIdx.x >> 6] = v;
  __syncthreads();
  return fmaxf(fmaxf(red4[0], red4[1]), fmaxf(red4[2], red4[3]));
}

// ---------------- zero scratch (sums/sumsq) ----------------
__global__ void zero_kernel(float* __restrict__ p) {
  p[blockIdx.x * 256 + threadIdx.x] = 0.f;
}

// ---------------- 1: cam[b,k,hw] = sum_c x[b,c,hw]*w[k,c] + bias[k] ----------------
// grid = B*64 blocks of 128 threads (128 pixels per block). Weights transposed
// into LDS [c][k(pad20)] so the 19 k-values per c are contiguous (b128 reads, broadcast).
__global__ __launch_bounds__(128) void cam_kernel(const float* __restrict__ x,
                                                  const float* __restrict__ w,
                                                  const float* __restrict__ bias,
                                                  float* __restrict__ cam) {
  __shared__ __align__(16) float wl[512 * 20];
  __shared__ float bl[20];
  int tid = threadIdx.x;
  for (int e = tid; e < K_ * C_; e += 128) {
    int k = e >> 9, c = e & 511;
    wl[c * 20 + k] = w[e];
  }
  if (tid < K_) bl[tid] = bias[tid];
  __syncthreads();
  int b = blockIdx.x >> 6;
  int pix = ((blockIdx.x & 63) << 7) + tid;
  const float* xp = x + (size_t)b * C_ * HW_ + pix;
  float acc[K_];
#pragma unroll
  for (int k = 0; k < K_; k++) acc[k] = bl[k];
#pragma unroll 4
  for (int c = 0; c < C_; c++) {
    float xv = xp[(size_t)c * HW_];
    const float* wr = &wl[c * 20];
#pragma unroll
    for (int k = 0; k < K_; k++) acc[k] += wr[k] * xv;
  }
  float* cp = cam + (size_t)b * K_ * HW_ + pix;
#pragma unroll
  for (int k = 0; k < K_; k++) cp[(size_t)k * HW_] = acc[k];
}

// ---------------- 2: bin_conf[b,n,k] = sigmoid(mean over 32x32 patch of cam) ----------------
// grid = (b*8+n)*19+k = 1216 blocks
__global__ __launch_bounds__(256) void cls_kernel(const float* __restrict__ cam,
                                                  float* __restrict__ bconf) {
  __shared__ float red4[4];
  int bid = blockIdx.x;
  int k = bid % 19;
  int n = (bid / 19) & 7;
  int b = bid / 152;
  int bh = n >> 2, bw = n & 3;
  const float* base = cam + ((size_t)b * K_ + k) * HW_ + (bh * 32) * W_ + bw * 32;
  float s = 0.f;
#pragma unroll
  for (int j = 0; j < 4; j++) {
    int p = threadIdx.x + j * 256;
    s += base[(p >> 5) * W_ + (p & 31)];
  }
  float tot = blockSum256(s, red4);
  if (threadIdx.x == 0) {
    float m = tot * (1.f / 1024.f);
    bconf[bid] = 1.f / (1.f + __expf(-m));
  }
}

// ---------------- 3: pix_conf[b,n,k,p] = softmax_p(cam patch) ----------------
__global__ __launch_bounds__(256) void softmax_kernel(const float* __restrict__ cam,
                                                      float* __restrict__ pconf) {
  __shared__ float red4[4];
  int bid = blockIdx.x;
  int k = bid % 19;
  int n = (bid / 19) & 7;
  int b = bid / 152;
  int bh = n >> 2, bw = n & 3;
  const float* base = cam + ((size_t)b * K_ + k) * HW_ + (bh * 32) * W_ + bw * 32;
  float v[4];
  float mx = -1e30f;
#pragma unroll
  for (int j = 0; j < 4; j++) {
    int p = threadIdx.x + j * 256;
    v[j] = base[(p >> 5) * W_ + (p & 31)];
    mx = fmaxf(mx, v[j]);
  }
  mx = blockMax256(mx, red4);
  float e[4];
  float se = 0.f;
#pragma unroll
  for (int j = 0; j < 4; j++) { e[j] = __expf(v[j] - mx); se += e[j]; }
  se = blockSum256(se, red4);
  float inv = 1.f / se;
  float* outp = pconf + (size_t)bid * P_;
#pragma unroll
  for (int j = 0; j < 4; j++) outp[threadIdx.x + j * 256] = e[j] * inv;
}

// ---------------- 4: local[b,n,k,c] = bin_conf * sum_p pc[b,n,k,p]*x_p[b,n,p,c] ----------------
// grid = (b*8+n)*2+half = 128 blocks; thread owns channel c; pc chunk staged in LDS.
__global__ __launch_bounds__(256) void local_kernel(const float* __restrict__ x,
                                                    const float* __restrict__ pconf,
                                                    const float* __restrict__ bconf,
                                                    float* __restrict__ locl) {
  __shared__ __align__(16) float pcl[19 * 128];
  int bid = blockIdx.x;
  int half = bid & 1;
  int n = (bid >> 1) & 7;
  int b = bid >> 4;
  int tid = threadIdx.x;
  int c = half * 256 + tid;
  int bh = n >> 2, bw = n & 3;
  const float* xb = x + ((size_t)b * C_ + c) * HW_ + (bh * 32) * W_ + bw * 32;
  const float* pcb = pconf + (size_t)((b * N_ + n) * K_) * P_;
  float acc[K_];
#pragma unroll
  for (int k = 0; k < K_; k++) acc[k] = 0.f;
  for (int p0 = 0; p0 < P_; p0 += 128) {
    __syncthreads();
    for (int e = tid; e < 19 * 128; e += 256) {
      int k = e >> 7, pl = e & 127;
      pcl[e] = pcb[(size_t)k * P_ + p0 + pl];
    }
    __syncthreads();
    for (int pl = 0; pl < 128; pl += 4) {
      int pp = p0 + pl;
      float4 xv = *(const float4*)&xb[(pp >> 5) * W_ + (pp & 31)];
#pragma unroll
      for (int k = 0; k < K_; k++) {
        float4 pv = *(const float4*)&pcl[k * 128 + pl];
        acc[k] += pv.x * xv.x + pv.y * xv.y + pv.z * xv.z + pv.w * xv.w;
      }
    }
  }
  const float* bc = bconf + (b * N_ + n) * K_;
  float* lp = locl + (size_t)((b * N_ + n) * K_) * C_ + c;
#pragma unroll
  for (int k = 0; k < K_; k++) lp[(size_t)k * C_] = acc[k] * bc[k];
}

// ---------------- 5: GCN (conv over bins + prelu + linear) then key projection ----------------
// grid = 1216 blocks ((b*8+n)*19+k); per block: t row, local2 row (stored), key row.
__global__ __launch_bounds__(256) void gcn_key_kernel(const float* __restrict__ locl,
                                                      const float* __restrict__ gw1,
                                                      const float* __restrict__ ga,
                                                      const float* __restrict__ gw2,
                                                      const float* __restrict__ kw,
                                                      const float* __restrict__ kb,
                                                      float* __restrict__ locl2,
                                                      float* __restrict__ keyo) {
  __shared__ __align__(16) float tl[512];
  __shared__ __align__(16) float l2l[512];
  int bid = blockIdx.x;
  int k = bid % 19;
  int n = (bid / 19) & 7;
  int b = bid / 152;
  int tid = threadIdx.x;
  float w1r[8];
#pragma unroll
  for (int m = 0; m < 8; m++) w1r[m] = gw1[n * 8 + m];
  float an = ga[n];
  const float* lb = locl + ((size_t)(b * N_) * K_ + k) * C_;  // m stride = K_*C_
  for (int c = tid; c < C_; c += 256) {
    float v = 0.f;
#pragma unroll
    for (int m = 0; m < 8; m++) v += w1r[m] * lb[(size_t)m * K_ * C_ + c];
    v += lb[(size_t)n * K_ * C_ + c];
    tl[c] = fmaxf(v, 0.f) + an * fminf(v, 0.f);
  }
  __syncthreads();
  for (int d = tid; d < C_; d += 256) {
    const float* wr = gw2 + (size_t)d * C_;
    float s = 0.f;
    for (int c4 = 0; c4 < C_; c4 += 4) {
      float4 wv = *(const float4*)&wr[c4];
      float4 tv = *(const float4*)&tl[c4];
      s += wv.x * tv.x + wv.y * tv.y + wv.z * tv.z + wv.w * tv.w;
    }
    l2l[d] = s;
    locl2[(size_t)bid * C_ + d] = s;
  }
  __syncthreads();
  {
    int i = tid;  // CI_ == 256
    const float* wr = kw + (size_t)i * C_;
    float s = kb[i];
    for (int c4 = 0; c4 < C_; c4 += 4) {
      float4 wv = *(const float4*)&wr[c4];
      float4 tv = *(const float4*)&l2l[c4];
      s += wv.x * tv.x + wv.y * tv.y + wv.z * tv.z + wv.w * tv.w;
    }
    keyo[(size_t)bid * CI_ + i] = s;
  }
}

// ---------------- 6: glob (fuse bins + prelu) then val projection ----------------
// grid = b*19+k = 152 blocks
__global__ __launch_bounds__(256) void glob_val_kernel(const float* __restrict__ locl2,
                                                       const float* __restrict__ fw,
                                                       const float* __restrict__ fb,
                                                       const float* __restrict__ ra,
                                                       const float* __restrict__ vw,
                                                       const float* __restrict__ vb,
                                                       float* __restrict__ valo) {
  __shared__ __align__(16) float gl[512];
  int bid = blockIdx.x;
  int k = bid % 19;
  int b = bid / 19;
  int tid = threadIdx.x;
  float fwr[8];
#pragma unroll
  for (int m = 0; m < 8; m++) fwr[m] = fw[m];
  float fbv = fb[0], rav = ra[0];
  const float* lb = locl2 + ((size_t)(b * N_) * K_ + k) * C_;
  for (int c = tid; c < C_; c += 256) {
    float v = fbv;
#pragma unroll
    for (int m = 0; m < 8; m++) v += fwr[m] * lb[(size_t)m * K_ * C_ + c];
    gl[c] = fmaxf(v, 0.f) + rav * fminf(v, 0.f);
  }
  __syncthreads();
  int i = tid;
  const float* wr = vw + (size_t)i * C_;
  float s = vb[i];
  for (int c4 = 0; c4 < C_; c4 += 4) {
    float4 wv = *(const float4*)&wr[c4];
    float4 tv = *(const float4*)&gl[c4];
    s += wv.x * tv.x + wv.y * tv.y + wv.z * tv.z + wv.w * tv.w;
  }
  valo[(size_t)bid * CI_ + i] = s;
}

// ---------------- 7: attention: q = x_p@q_w^T+qb, s=q@key^T, softmax_k, o=s@val ----------------
// grid = ((b*8+n)*32+row) = 2048 blocks of 256; thread = (p = tid&31 pixel-in-row, g = tid>>5 owns 32 i's)
__global__ __launch_bounds__(256) void attn_kernel(const float* __restrict__ x,
                                                   const float* __restrict__ qw,
                                                   const float* __restrict__ qb,
                                                   const float* __restrict__ keyo,
                                                   const float* __restrict__ valo,
                                                   float* __restrict__ obuf) {
  __shared__ __align__(16) float keyl[19 * 256];
  __shared__ __align__(16) float vall[19 * 256];
  __shared__ float part[32 * 153];  // [p][g*19+k], stride 153 (odd vs 32 banks)
  __shared__ float sfin[32 * 21];   // [p][k], stride 21
  int bid = blockIdx.x;
  int row = bid & 31;
  int n = (bid >> 5) & 7;
  int b = bid >> 8;
  int tid = threadIdx.x;
  int p = tid & 31;
  int g = tid >> 5;
  int bh = n >> 2, bw = n & 3;
  int hwbase = (bh * 32 + row) * W_ + bw * 32;
  const float* keysrc = keyo + (size_t)((b * N_ + n) * K_) * CI_;
  const float* valsrc = valo + (size_t)(b * K_) * CI_;
  for (int e = tid; e < K_ * CI_; e += 256) {
    keyl[e] = keysrc[e];
    vall[e] = valsrc[e];
  }
  __syncthreads();
  float q[32];
#pragma unroll
  for (int il = 0; il < 32; il++) q[il] = qb[g * 32 + il];
  const float* xb = x + (size_t)b * C_ * HW_ + hwbase + p;
  for (int c0 = 0; c0 < C_; c0 += 64) {
    float xr[64];
#pragma unroll
    for (int cl = 0; cl < 64; cl++) xr[cl] = xb[(size_t)(c0 + cl) * HW_];
#pragma unroll
    for (int il = 0; il < 32; il++) {
      const float* wr = qw + (size_t)(g * 32 + il) * C_ + c0;
      float s0 = 0.f;
#pragma unroll
      for (int cl = 0; cl < 64; cl += 4) {
        float4 wv = *(const float4*)&wr[cl];
        s0 += wv.x * xr[cl] + wv.y * xr[cl + 1] + wv.z * xr[cl + 2] + wv.w * xr[cl + 3];
      }
      q[il] += s0;
    }
  }
  // partial scores over this thread's 32 i's
#pragma unroll
  for (int k = 0; k < K_; k++) {
    const float* kr = &keyl[k * CI_ + g * 32];
    float s = 0.f;
#pragma unroll
    for (int il = 0; il < 32; il++) s += q[il] * kr[il];
    part[p * 153 + g * 19 + k] = s;
  }
  __syncthreads();
  if (tid < 32) {
    float sv[K_];
    float mx = -1e30f;
#pragma unroll
    for (int k = 0; k < K_; k++) {
      float s = 0.f;
#pragma unroll
      for (int gg = 0; gg < 8; gg++) s += part[tid * 153 + gg * 19 + k];
      sv[k] = s;
      mx = fmaxf(mx, s);
    }
    float se = 0.f;
#pragma unroll
    for (int k = 0; k < K_; k++) {
      sv[k] = __expf(sv[k] - mx);
      se += sv[k];
    }
    float inv = 1.f / se;
#pragma unroll
    for (int k = 0; k < K_; k++) sfin[tid * 21 + k] = sv[k] * inv;
  }
  __syncthreads();
  float o[32];
#pragma unroll
  for (int il = 0; il < 32; il++) o[il] = 0.f;
#pragma unroll
  for (int k = 0; k < K_; k++) {
    float a = sfin[p * 21 + k];
    const float* vr = &vall[k * CI_ + g * 32];
#pragma unroll
    for (int il = 0; il < 32; il++) o[il] += a * vr[il];
  }
  // write patch-recovered layout [b][i][H][W]
  float* ob = obuf + (size_t)b * CI_ * HW_ + hwbase + p;
#pragma unroll
  for (int il = 0; il < 32; il++) ob[(size_t)(g * 32 + il) * HW_] = o[il];
}

// ---------------- 8: y[b,c,hw] = sum_i obuf[b,i,hw]*ow[c,i]  (writes into d_out as scratch) ----------------
// grid = b*256+tile = 2048 blocks of 512; thread = (p = tid&31, g = tid>>5 owns 32 c's)
__global__ __launch_bounds__(512) void yconv_kernel(const float* __restrict__ obuf,
                                                    const float* __restrict__ ow,
                                                    float* __restrict__ y) {
  int bid = blockIdx.x;
  int tile = bid & 255;
  int b = bid >> 8;
  int tid = threadIdx.x;
  int p = tid & 31;
  int g = tid >> 5;  // 0..15
  int hw = tile * 32 + p;
  const float* ob = obuf + (size_t)b * CI_ * HW_ + hw;
  float acc[32];
#pragma unroll
  for (int cl = 0; cl < 32; cl++) acc[cl] = 0.f;
  for (int i0 = 0; i0 < CI_; i0 += 32) {
    float orr[32];
#pragma unroll
    for (int il = 0; il < 32; il++) orr[il] = ob[(size_t)(i0 + il) * HW_];
#pragma unroll
    for (int cl = 0; cl < 32; cl++) {
      const float* wr = ow + (size_t)(g * 32 + cl) * CI_ + i0;
      float s = 0.f;
#pragma unroll
      for (int il = 0; il < 32; il += 4) {
        float4 wv = *(const float4*)&wr[il];
        s += wv.x * orr[il] + wv.y * orr[il + 1] + wv.z * orr[il + 2] + wv.w * orr[il + 3];
      }
      acc[cl] += s;
    }
  }
  float* yb = y + (size_t)b * C_ * HW_ + hw;
#pragma unroll
  for (int cl = 0; cl < 32; cl++) yb[(size_t)(g * 32 + cl) * HW_] = acc[cl];
}

// ---------------- 9: per-channel sum / sumsq of y ----------------
// grid = slice*512+c = 2048 blocks of 256
__global__ __launch_bounds__(256) void bnstats_kernel(const float* __restrict__ y,
                                                      float* __restrict__ sums,
                                                      float* __restrict__ sumsq) {
  __shared__ float red4[4];
  int c = blockIdx.x & 511;
  int slice = blockIdx.x >> 9;
  float s = 0.f, q = 0.f;
  for (int b = 0; b < B_; b++) {
    const float* yb = y + ((size_t)b * C_ + c) * HW_ + slice * 2048;
    for (int j = threadIdx.x; j < 2048; j += 256) {
      float v = yb[j];
      s += v;
      q += v * v;
    }
  }
  float ts = blockSum256(s, red4);
  float tq = blockSum256(q, red4);
  if (threadIdx.x == 0) {
    atomicAdd(&sums[c], ts);
    atomicAdd(&sumsq[c], tq);
  }
}

// ---------------- 10: finalize BN scale/shift ----------------
__global__ __launch_bounds__(512) void bnfinal_kernel(const float* __restrict__ sums,
                                                      const float* __restrict__ sumsq,
                                                      const float* __restrict__ gamma,
                                                      const float* __restrict__ beta,
                                                      float* __restrict__ scale,
                                                      float* __restrict__ shift) {
  int c = threadIdx.x;
  const float inv_cnt = 1.f / 65536.f;  // B*H*W
  float mu = sums[c] * inv_cnt;
  float var = sumsq[c] * inv_cnt - mu * mu;
  float iv = rsqrtf(var + 1e-5f);
  float sc = gamma[c] * iv;
  scale[c] = sc;
  shift[c] = beta[c] - mu * sc;
}

// ---------------- 11: out = x + prelu(y*scale+shift, out_a[c])  (y lives in d_out) ----------------
__global__ __launch_bounds__(256) void final_kernel(const float* __restrict__ x,
                                                    const float* __restrict__ scale,
                                                    const float* __restrict__ shift,
                                                    const float* __restrict__ oa,
                                                    float* __restrict__ out) {
  size_t idx = ((size_t)blockIdx.x * 256 + threadIdx.x) * 4;
  int c = (int)((idx >> 13) & 511);  // HW_ = 8192 = 2^13
  float sc = scale[c], sh = shift[c], a = oa[c];
  float4 y = *(float4*)&out[idx];
  float4 xv = *(const float4*)&x[idx];
  float4 r;
  float t;
  t = y.x * sc + sh; r.x = xv.x + fmaxf(t, 0.f) + a * fminf(t, 0.f);
  t = y.y * sc + sh; r.y = xv.y + fmaxf(t, 0.f) + a * fminf(t, 0.f);
  t = y.z * sc + sh; r.z = xv.z + fmaxf(t, 0.f) + a * fminf(t, 0.f);
  t = y.w * sc + sh; r.w = xv.w + fmaxf(t, 0.f) + a * fminf(t, 0.f);
  *(float4*)&out[idx] = r;
}

extern "C" void kernel_launch(void* const* d_in, const int* in_sizes, int n_in,
                              void* d_out, int out_size, void* d_ws, size_t ws_size,
                              hipStream_t stream) {
  const float* x     = (const float*)d_in[0];
  const float* camw  = (const float*)d_in[1];
  const float* camb  = (const float*)d_in[2];
  const float* gw1   = (const float*)d_in[3];
  const float* ga    = (const float*)d_in[4];
  const float* gw2   = (const float*)d_in[5];
  const float* fw    = (const float*)d_in[6];
  const float* fb    = (const float*)d_in[7];
  const float* ra    = (const float*)d_in[8];
  const float* qw    = (const float*)d_in[9];
  const float* qb    = (const float*)d_in[10];
  const float* kw    = (const float*)d_in[11];
  const float* kb    = (const float*)d_in[12];
  const float* vw    = (const float*)d_in[13];
  const float* vb    = (const float*)d_in[14];
  const float* ow    = (const float*)d_in[15];
  const float* gamma = (const float*)d_in[16];
  const float* beta  = (const float*)d_in[17];
  const float* oa    = (const float*)d_in[18];
  float* out = (float*)d_out;
  float* ws = (float*)d_ws;

  // workspace layout (floats)
  float* cam   = ws;                   // 1245184  [B][K][HW]
  float* bconf = cam + 1245184;        // 1216 (pad 2048)  [(b*8+n)*19+k]
  float* pconf = bconf + 2048;         // 1245184  [(b*8+n)*19+k][1024]
  float* locl  = pconf + 1245184;      // 622592   [(b*8+n)*19+k][512]
  float* locl2 = locl + 622592;        // 622592
  float* keyo  = locl2 + 622592;       // 311296   [(b*8+n)*19+k][256]
  float* valo  = keyo + 311296;        // 38912    [b*19+k][256]
  float* obuf  = valo + 38912;         // 16777216 [B][CI][HW]
  float* sums  = obuf + 16777216;      // 512
  float* sumsq = sums + 512;           // 512
  float* scale = sumsq + 512;          // 512
  float* shift = scale + 512;          // 512

  zero_kernel<<<4, 256, 0, stream>>>(sums);  // zeroes sums+sumsq (1024 floats)
  cam_kernel<<<512, 128, 0, stream>>>(x, camw, camb, cam);
  cls_kernel<<<1216, 256, 0, stream>>>(cam, bconf);
  softmax_kernel<<<1216, 256, 0, stream>>>(cam, pconf);
  local_kernel<<<128, 256, 0, stream>>>(x, pconf, bconf, locl);
  gcn_key_kernel<<<1216, 256, 0, stream>>>(locl, gw1, ga, gw2, kw, kb, locl2, keyo);
  glob_val_kernel<<<152, 256, 0, stream>>>(locl2, fw, fb, ra, vw, vb, valo);
  attn_kernel<<<2048, 256, 0, stream>>>(x, qw, qb, keyo, valo, obuf);
  yconv_kernel<<<2048, 512, 0, stream>>>(obuf, ow, out);
  bnstats_kernel<<<2048, 256, 0, stream>>>(out, sums, sumsq);
  bnfinal_kernel<<<1, 512, 0, stream>>>(sums, sumsq, gamma, beta, scale, shift);
  final_kernel<<<32768, 256, 0, stream>>>(x, scale, shift, oa, out);
}

// Round 2
// 887.046 us; speedup vs baseline: 3.3975x; 3.3975x over previous
//
#include <hip/hip_runtime.h>
#include <cstdint>
#include <cstddef>

#define B_ 8
#define C_ 512
#define H_ 64
#define W_ 128
#define HW_ 8192
#define K_ 19
#define N_ 8
#define P_ 1024
#define CI_ 256

typedef unsigned short u16;
typedef unsigned int u32;
typedef __attribute__((ext_vector_type(8))) short bf16x8;   // 8 bf16 (4 VGPRs)
typedef __attribute__((ext_vector_type(4))) float f32x4;    // 4 fp32 acc

__device__ __forceinline__ u16 f2bf(float f) {
  u32 u = __float_as_uint(f);
  u32 r = (u + 0x7FFFu + ((u >> 16) & 1u)) >> 16;
  return (u16)r;
}
__device__ __forceinline__ float bf2f(u16 h) {
  return __uint_as_float(((u32)h) << 16);
}

// ---------------- block reductions (256 threads = 4 waves) ----------------
__device__ __forceinline__ float blockSum256(float v, float* red4) {
#pragma unroll
  for (int o = 32; o > 0; o >>= 1) v += __shfl_down(v, o, 64);
  __syncthreads();
  if ((threadIdx.x & 63) == 0) red4[threadIdx.x >> 6] = v;
  __syncthreads();
  return red4[0] + red4[1] + red4[2] + red4[3];
}

__device__ __forceinline__ float blockMax256(float v, float* red4) {
#pragma unroll
  for (int o = 32; o > 0; o >>= 1) v = fmaxf(v, __shfl_down(v, o, 64));
  __syncthreads();
  if ((threadIdx.x & 63) == 0) red4[threadIdx.x >> 6] = v;
  __syncthreads();
  return fmaxf(fmaxf(red4[0], red4[1]), fmaxf(red4[2], red4[3]));
}

__global__ void zero_kernel(float* __restrict__ p) {
  p[blockIdx.x * 256 + threadIdx.x] = 0.f;
}

// ---------------- convert weights fp32 -> bf16 ----------------
__global__ __launch_bounds__(256) void w2bf_kernel(const float* __restrict__ a,
                                                   u16* __restrict__ o) {
  int i = blockIdx.x * 256 + threadIdx.x;
  o[i] = f2bf(a[i]);
}

// ---------------- transpose x [b,c,hw] -> xt bf16 [b,hw,c] ----------------
// 64x64 tiles; grid = 8 b * 8 (c/64) * 128 (hw/64) = 8192 blocks
__global__ __launch_bounds__(256) void xpose_kernel(const float* __restrict__ x,
                                                    u16* __restrict__ xt) {
  __shared__ float tile[64][65];
  int bid = blockIdx.x;
  int hw0 = (bid & 127) << 6;
  int c0 = ((bid >> 7) & 7) << 6;
  int b = bid >> 10;
  int tid = threadIdx.x;
  int r = tid >> 4;             // 0..15
  int col4 = (tid & 15) << 2;   // 0..60
  const float* xb = x + ((size_t)b * C_ + c0) * HW_ + hw0;
#pragma unroll
  for (int it = 0; it < 4; it++) {
    int rr = r + it * 16;  // c-row
    float4 v = *(const float4*)&xb[(size_t)rr * HW_ + col4];
    tile[rr][col4 + 0] = v.x;
    tile[rr][col4 + 1] = v.y;
    tile[rr][col4 + 2] = v.z;
    tile[rr][col4 + 3] = v.w;
  }
  __syncthreads();
  u16* xo = xt + ((size_t)b * HW_ + hw0) * C_ + c0;
#pragma unroll
  for (int it = 0; it < 4; it++) {
    int hwr = r + it * 16;  // hw-row
    ushort4 o;
    o.x = f2bf(tile[col4 + 0][hwr]);
    o.y = f2bf(tile[col4 + 1][hwr]);
    o.z = f2bf(tile[col4 + 2][hwr]);
    o.w = f2bf(tile[col4 + 3][hwr]);
    *(ushort4*)&xo[(size_t)hwr * C_ + col4] = o;
  }
}

// ---------------- 1: cam[b,k,hw] = sum_c x[b,c,hw]*w[k,c] + bias[k] ----------------
__global__ __launch_bounds__(128) void cam_kernel(const float* __restrict__ x,
                                                  const float* __restrict__ w,
                                                  const float* __restrict__ bias,
                                                  float* __restrict__ cam) {
  __shared__ __align__(16) float wl[512 * 20];
  __shared__ float bl[20];
  int tid = threadIdx.x;
  for (int e = tid; e < K_ * C_; e += 128) {
    int k = e >> 9, c = e & 511;
    wl[c * 20 + k] = w[e];
  }
  if (tid < K_) bl[tid] = bias[tid];
  __syncthreads();
  int b = blockIdx.x >> 6;
  int pix = ((blockIdx.x & 63) << 7) + tid;
  const float* xp = x + (size_t)b * C_ * HW_ + pix;
  float acc[K_];
#pragma unroll
  for (int k = 0; k < K_; k++) acc[k] = bl[k];
#pragma unroll 4
  for (int c = 0; c < C_; c++) {
    float xv = xp[(size_t)c * HW_];
    const float* wr = &wl[c * 20];
#pragma unroll
    for (int k = 0; k < K_; k++) acc[k] += wr[k] * xv;
  }
  float* cp = cam + (size_t)b * K_ * HW_ + pix;
#pragma unroll
  for (int k = 0; k < K_; k++) cp[(size_t)k * HW_] = acc[k];
}

// ---------------- 2: bin_conf ----------------
__global__ __launch_bounds__(256) void cls_kernel(const float* __restrict__ cam,
                                                  float* __restrict__ bconf) {
  __shared__ float red4[4];
  int bid = blockIdx.x;
  int k = bid % 19;
  int n = (bid / 19) & 7;
  int b = bid / 152;
  int bh = n >> 2, bw = n & 3;
  const float* base = cam + ((size_t)b * K_ + k) * HW_ + (bh * 32) * W_ + bw * 32;
  float s = 0.f;
#pragma unroll
  for (int j = 0; j < 4; j++) {
    int p = threadIdx.x + j * 256;
    s += base[(p >> 5) * W_ + (p & 31)];
  }
  float tot = blockSum256(s, red4);
  if (threadIdx.x == 0) {
    float m = tot * (1.f / 1024.f);
    bconf[bid] = 1.f / (1.f + __expf(-m));
  }
}

// ---------------- 3: pix_conf softmax over patch ----------------
__global__ __launch_bounds__(256) void softmax_kernel(const float* __restrict__ cam,
                                                      float* __restrict__ pconf) {
  __shared__ float red4[4];
  int bid = blockIdx.x;
  int k = bid % 19;
  int n = (bid / 19) & 7;
  int b = bid / 152;
  int bh = n >> 2, bw = n & 3;
  const float* base = cam + ((size_t)b * K_ + k) * HW_ + (bh * 32) * W_ + bw * 32;
  float v[4];
  float mx = -1e30f;
#pragma unroll
  for (int j = 0; j < 4; j++) {
    int p = threadIdx.x + j * 256;
    v[j] = base[(p >> 5) * W_ + (p & 31)];
    mx = fmaxf(mx, v[j]);
  }
  mx = blockMax256(mx, red4);
  float e[4];
  float se = 0.f;
#pragma unroll
  for (int j = 0; j < 4; j++) { e[j] = __expf(v[j] - mx); se += e[j]; }
  se = blockSum256(se, red4);
  float inv = 1.f / se;
  float* outp = pconf + (size_t)bid * P_;
#pragma unroll
  for (int j = 0; j < 4; j++) outp[threadIdx.x + j * 256] = e[j] * inv;
}

// ---------------- 4: local ----------------
__global__ __launch_bounds__(256) void local_kernel(const float* __restrict__ x,
                                                    const float* __restrict__ pconf,
                                                    const float* __restrict__ bconf,
                                                    float* __restrict__ locl) {
  __shared__ __align__(16) float pcl[19 * 128];
  int bid = blockIdx.x;
  int half = bid & 1;
  int n = (bid >> 1) & 7;
  int b = bid >> 4;
  int tid = threadIdx.x;
  int c = half * 256 + tid;
  int bh = n >> 2, bw = n & 3;
  const float* xb = x + ((size_t)b * C_ + c) * HW_ + (bh * 32) * W_ + bw * 32;
  const float* pcb = pconf + (size_t)((b * N_ + n) * K_) * P_;
  float acc[K_];
#pragma unroll
  for (int k = 0; k < K_; k++) acc[k] = 0.f;
  for (int p0 = 0; p0 < P_; p0 += 128) {
    __syncthreads();
    for (int e = tid; e < 19 * 128; e += 256) {
      int k = e >> 7, pl = e & 127;
      pcl[e] = pcb[(size_t)k * P_ + p0 + pl];
    }
    __syncthreads();
    for (int pl = 0; pl < 128; pl += 4) {
      int pp = p0 + pl;
      float4 xv = *(const float4*)&xb[(pp >> 5) * W_ + (pp & 31)];
#pragma unroll
      for (int k = 0; k < K_; k++) {
        float4 pv = *(const float4*)&pcl[k * 128 + pl];
        acc[k] += pv.x * xv.x + pv.y * xv.y + pv.z * xv.z + pv.w * xv.w;
      }
    }
  }
  const float* bc = bconf + (b * N_ + n) * K_;
  float* lp = locl + (size_t)((b * N_ + n) * K_) * C_ + c;
#pragma unroll
  for (int k = 0; k < K_; k++) lp[(size_t)k * C_] = acc[k] * bc[k];
}

// ---------------- 5: GCN + key ----------------
__global__ __launch_bounds__(256) void gcn_key_kernel(const float* __restrict__ locl,
                                                      const float* __restrict__ gw1,
                                                      const float* __restrict__ ga,
                                                      const float* __restrict__ gw2,
                                                      const float* __restrict__ kw,
                                                      const float* __restrict__ kb,
                                                      float* __restrict__ locl2,
                                                      float* __restrict__ keyo) {
  __shared__ __align__(16) float tl[512];
  __shared__ __align__(16) float l2l[512];
  int bid = blockIdx.x;
  int k = bid % 19;
  int n = (bid / 19) & 7;
  int b = bid / 152;
  int tid = threadIdx.x;
  float w1r[8];
#pragma unroll
  for (int m = 0; m < 8; m++) w1r[m] = gw1[n * 8 + m];
  float an = ga[n];
  const float* lb = locl + ((size_t)(b * N_) * K_ + k) * C_;
  for (int c = tid; c < C_; c += 256) {
    float v = 0.f;
#pragma unroll
    for (int m = 0; m < 8; m++) v += w1r[m] * lb[(size_t)m * K_ * C_ + c];
    v += lb[(size_t)n * K_ * C_ + c];
    tl[c] = fmaxf(v, 0.f) + an * fminf(v, 0.f);
  }
  __syncthreads();
  for (int d = tid; d < C_; d += 256) {
    const float* wr = gw2 + (size_t)d * C_;
    float s = 0.f;
    for (int c4 = 0; c4 < C_; c4 += 4) {
      float4 wv = *(const float4*)&wr[c4];
      float4 tv = *(const float4*)&tl[c4];
      s += wv.x * tv.x + wv.y * tv.y + wv.z * tv.z + wv.w * tv.w;
    }
    l2l[d] = s;
    locl2[(size_t)bid * C_ + d] = s;
  }
  __syncthreads();
  {
    int i = tid;
    const float* wr = kw + (size_t)i * C_;
    float s = kb[i];
    for (int c4 = 0; c4 < C_; c4 += 4) {
      float4 wv = *(const float4*)&wr[c4];
      float4 tv = *(const float4*)&l2l[c4];
      s += wv.x * tv.x + wv.y * tv.y + wv.z * tv.z + wv.w * tv.w;
    }
    keyo[(size_t)bid * CI_ + i] = s;
  }
}

// ---------------- 6: glob + val ----------------
__global__ __launch_bounds__(256) void glob_val_kernel(const float* __restrict__ locl2,
                                                       const float* __restrict__ fw,
                                                       const float* __restrict__ fb,
                                                       const float* __restrict__ ra,
                                                       const float* __restrict__ vw,
                                                       const float* __restrict__ vb,
                                                       float* __restrict__ valo) {
  __shared__ __align__(16) float gl[512];
  int bid = blockIdx.x;
  int k = bid % 19;
  int b = bid / 19;
  int tid = threadIdx.x;
  float fwr[8];
#pragma unroll
  for (int m = 0; m < 8; m++) fwr[m] = fw[m];
  float fbv = fb[0], rav = ra[0];
  const float* lb = locl2 + ((size_t)(b * N_) * K_ + k) * C_;
  for (int c = tid; c < C_; c += 256) {
    float v = fbv;
#pragma unroll
    for (int m = 0; m < 8; m++) v += fwr[m] * lb[(size_t)m * K_ * C_ + c];
    gl[c] = fmaxf(v, 0.f) + rav * fminf(v, 0.f);
  }
  __syncthreads();
  int i = tid;
  const float* wr = vw + (size_t)i * C_;
  float s = vb[i];
  for (int c4 = 0; c4 < C_; c4 += 4) {
    float4 wv = *(const float4*)&wr[c4];
    float4 tv = *(const float4*)&gl[c4];
    s += wv.x * tv.x + wv.y * tv.y + wv.z * tv.z + wv.w * tv.w;
  }
  valo[(size_t)bid * CI_ + i] = s;
}

// ---------------- MFMA GEMM: C[m][n] = sum_k A[m][k]*Bw[n][k] (+bias[n]) ----------------
// A: bf16 [b][8192][KDIM] row-major; Bw: bf16 [NDIM][KDIM] row-major.
// TRANS_OUT: write fp32 C[b][n][m] (ld 8192); else write C[b][m][n] (ld NDIM), bf16 if OUTBF16.
// 128x128 block tile, 4 waves (2x2), each wave 64x64 via 4x4 mfma_16x16x32.
template <int KDIM, int NDIM, bool TRANS_OUT, bool BIAS, bool OUTBF16>
__global__ __launch_bounds__(256) void gemm_kernel(const u16* __restrict__ A,
                                                   const u16* __restrict__ Bw,
                                                   const float* __restrict__ bias,
                                                   void* __restrict__ Cout) {
  __shared__ u16 As[128 * 72];  // stride 72 bf16 = 144 B (2-way-conflict LDS)
  __shared__ u16 Bs[128 * 72];
  constexpr int NT = NDIM / 128;
  int b = blockIdx.y;
  int m0 = (blockIdx.x / NT) * 128;
  int n0 = (blockIdx.x % NT) * 128;
  int tid = threadIdx.x;
  int wave = tid >> 6, lane = tid & 63;
  int wm = (wave >> 1) * 64, wn = (wave & 1) * 64;
  int quad = lane >> 4, l16 = lane & 15;
  const u16* Ab = A + (size_t)b * 8192 * KDIM + (size_t)m0 * KDIM;
  const u16* Bb = Bw + (size_t)n0 * KDIM;
  f32x4 acc[4][4] = {};
  int sr = tid >> 3;
  int sk = (tid & 7) * 8;
  for (int k0 = 0; k0 < KDIM; k0 += 64) {
    __syncthreads();
#pragma unroll
    for (int it = 0; it < 4; it++) {
      int r = sr + it * 32;
      *(uint4*)&As[r * 72 + sk] = *(const uint4*)&Ab[(size_t)r * KDIM + k0 + sk];
      *(uint4*)&Bs[r * 72 + sk] = *(const uint4*)&Bb[(size_t)r * KDIM + k0 + sk];
    }
    __syncthreads();
#pragma unroll
    for (int kk = 0; kk < 2; kk++) {
      bf16x8 af[4], bfv[4];
#pragma unroll
      for (int t = 0; t < 4; t++) {
        af[t] = *(const bf16x8*)&As[(wm + t * 16 + l16) * 72 + kk * 32 + quad * 8];
        bfv[t] = *(const bf16x8*)&Bs[(wn + t * 16 + l16) * 72 + kk * 32 + quad * 8];
      }
#pragma unroll
      for (int tm = 0; tm < 4; tm++)
#pragma unroll
        for (int tn = 0; tn < 4; tn++)
          acc[tm][tn] = __builtin_amdgcn_mfma_f32_16x16x32_bf16(af[tm], bfv[tn], acc[tm][tn], 0, 0, 0);
    }
  }
  if constexpr (!TRANS_OUT) {
    float bv[4];
#pragma unroll
    for (int tn = 0; tn < 4; tn++)
      bv[tn] = BIAS ? bias[n0 + wn + tn * 16 + l16] : 0.f;
#pragma unroll
    for (int tm = 0; tm < 4; tm++) {
      int mm = m0 + wm + tm * 16 + quad * 4;
#pragma unroll
      for (int tn = 0; tn < 4; tn++) {
        int nn = n0 + wn + tn * 16 + l16;
        if constexpr (OUTBF16) {
          u16* C = (u16*)Cout + (size_t)b * 8192 * NDIM;
#pragma unroll
          for (int reg = 0; reg < 4; reg++)
            C[(size_t)(mm + reg) * NDIM + nn] = f2bf(acc[tm][tn][reg] + bv[tn]);
        } else {
          float* C = (float*)Cout + (size_t)b * 8192 * NDIM;
#pragma unroll
          for (int reg = 0; reg < 4; reg++)
            C[(size_t)(mm + reg) * NDIM + nn] = acc[tm][tn][reg] + bv[tn];
        }
      }
    }
  } else {
    float* C = (float*)Cout + (size_t)b * NDIM * 8192;
#pragma unroll
    for (int tm = 0; tm < 4; tm++) {
      int mm = m0 + wm + tm * 16 + quad * 4;
#pragma unroll
      for (int tn = 0; tn < 4; tn++) {
        int nn = n0 + wn + tn * 16 + l16;
        *(f32x4*)&C[(size_t)nn * 8192 + mm] = acc[tm][tn];
      }
    }
  }
}

// ---------------- attention: scores, softmax(19), out = aff@val ----------------
// grid = ((b*8+n)*8 + rowgrp) = 512 blocks; 128 pixels per block (4 bin-rows x 32).
__global__ __launch_bounds__(256) void attn2_kernel(const u16* __restrict__ q,
                                                    const float* __restrict__ keyo,
                                                    const float* __restrict__ valo,
                                                    u16* __restrict__ obuf) {
  __shared__ float keyl[19 * 256];
  __shared__ float vall[19 * 256];
  __shared__ float aff[128 * 20];
  int bid = blockIdx.x;
  int rg = bid & 7;
  int n = (bid >> 3) & 7;
  int b = bid >> 6;
  int bh = n >> 2, bw = n & 3;
  int tid = threadIdx.x;
  const float* ksrc = keyo + (size_t)((b * 8 + n) * 19) * 256;
  for (int e = tid; e < 19 * 256; e += 256) keyl[e] = ksrc[e];
  __syncthreads();
  if (tid < 128) {
    int r = rg * 4 + (tid >> 5);
    int wc = tid & 31;
    int hw = (bh * 32 + r) * W_ + bw * 32 + wc;
    const u16* qr = q + ((size_t)b * HW_ + hw) * 256;
    float acc[19];
#pragma unroll
    for (int k = 0; k < 19; k++) acc[k] = 0.f;
    for (int i0 = 0; i0 < 256; i0 += 8) {
      uint4 v = *(const uint4*)&qr[i0];
      float f0 = __uint_as_float((v.x & 0xFFFFu) << 16);
      float f1 = __uint_as_float(v.x & 0xFFFF0000u);
      float f2 = __uint_as_float((v.y & 0xFFFFu) << 16);
      float f3 = __uint_as_float(v.y & 0xFFFF0000u);
      float f4 = __uint_as_float((v.z & 0xFFFFu) << 16);
      float f5 = __uint_as_float(v.z & 0xFFFF0000u);
      float f6 = __uint_as_float((v.w & 0xFFFFu) << 16);
      float f7 = __uint_as_float(v.w & 0xFFFF0000u);
#pragma unroll
      for (int k = 0; k < 19; k++) {
        const float* kr = &keyl[k * 256 + i0];
        acc[k] += f0 * kr[0] + f1 * kr[1] + f2 * kr[2] + f3 * kr[3] +
                  f4 * kr[4] + f5 * kr[5] + f6 * kr[6] + f7 * kr[7];
      }
    }
    float mx = -1e30f;
#pragma unroll
    for (int k = 0; k < 19; k++) mx = fmaxf(mx, acc[k]);
    float se = 0.f;
#pragma unroll
    for (int k = 0; k < 19; k++) { acc[k] = __expf(acc[k] - mx); se += acc[k]; }
    float inv = 1.f / se;
#pragma unroll
    for (int k = 0; k < 19; k++) aff[tid * 20 + k] = acc[k] * inv;
  } else {
    const float* vsrc = valo + (size_t)b * 19 * 256;
    for (int e = tid - 128; e < 19 * 256; e += 128) vall[e] = vsrc[e];
  }
  __syncthreads();
  // output: thread t -> pixel (t&127), i-half (t>>7); wave-uniform ih for LDS broadcast
  int px = tid & 127;
  int ih = (tid >> 7) * 128;
  int r3 = rg * 4 + (px >> 5);
  int wc3 = px & 31;
  int hw3 = (bh * 32 + r3) * W_ + bw * 32 + wc3;
  float av[19];
#pragma unroll
  for (int k = 0; k < 19; k++) av[k] = aff[px * 20 + k];
  u16* ob = obuf + ((size_t)b * HW_ + hw3) * 256 + ih;
  for (int i0 = 0; i0 < 128; i0 += 16) {
    float o16[16];
#pragma unroll
    for (int j = 0; j < 16; j++) o16[j] = 0.f;
#pragma unroll
    for (int k = 0; k < 19; k++) {
      float a = av[k];
      const float* vr = &vall[k * 256 + ih + i0];
#pragma unroll
      for (int j = 0; j < 16; j++) o16[j] += a * vr[j];
    }
    uint4 w0, w1;
    w0.x = (u32)f2bf(o16[0]) | ((u32)f2bf(o16[1]) << 16);
    w0.y = (u32)f2bf(o16[2]) | ((u32)f2bf(o16[3]) << 16);
    w0.z = (u32)f2bf(o16[4]) | ((u32)f2bf(o16[5]) << 16);
    w0.w = (u32)f2bf(o16[6]) | ((u32)f2bf(o16[7]) << 16);
    w1.x = (u32)f2bf(o16[8]) | ((u32)f2bf(o16[9]) << 16);
    w1.y = (u32)f2bf(o16[10]) | ((u32)f2bf(o16[11]) << 16);
    w1.z = (u32)f2bf(o16[12]) | ((u32)f2bf(o16[13]) << 16);
    w1.w = (u32)f2bf(o16[14]) | ((u32)f2bf(o16[15]) << 16);
    *(uint4*)&ob[i0] = w0;
    *(uint4*)&ob[i0 + 8] = w1;
  }
}

// ---------------- BN stats ----------------
__global__ __launch_bounds__(256) void bnstats_kernel(const float* __restrict__ y,
                                                      float* __restrict__ sums,
                                                      float* __restrict__ sumsq) {
  __shared__ float red4[4];
  int c = blockIdx.x & 511;
  int slice = blockIdx.x >> 9;
  float s = 0.f, q = 0.f;
  for (int b = 0; b < B_; b++) {
    const float* yb = y + ((size_t)b * C_ + c) * HW_ + slice * 2048;
    for (int j = threadIdx.x; j < 2048; j += 256) {
      float v = yb[j];
      s += v;
      q += v * v;
    }
  }
  float ts = blockSum256(s, red4);
  float tq = blockSum256(q, red4);
  if (threadIdx.x == 0) {
    atomicAdd(&sums[c], ts);
    atomicAdd(&sumsq[c], tq);
  }
}

__global__ __launch_bounds__(512) void bnfinal_kernel(const float* __restrict__ sums,
                                                      const float* __restrict__ sumsq,
                                                      const float* __restrict__ gamma,
                                                      const float* __restrict__ beta,
                                                      float* __restrict__ scale,
                                                      float* __restrict__ shift) {
  int c = threadIdx.x;
  const float inv_cnt = 1.f / 65536.f;
  float mu = sums[c] * inv_cnt;
  float var = sumsq[c] * inv_cnt - mu * mu;
  float iv = rsqrtf(var + 1e-5f);
  float sc = gamma[c] * iv;
  scale[c] = sc;
  shift[c] = beta[c] - mu * sc;
}

__global__ __launch_bounds__(256) void final_kernel(const float* __restrict__ x,
                                                    const float* __restrict__ scale,
                                                    const float* __restrict__ shift,
                                                    const float* __restrict__ oa,
                                                    float* __restrict__ out) {
  size_t idx = ((size_t)blockIdx.x * 256 + threadIdx.x) * 4;
  int c = (int)((idx >> 13) & 511);
  float sc = scale[c], sh = shift[c], a = oa[c];
  float4 y = *(float4*)&out[idx];
  float4 xv = *(const float4*)&x[idx];
  float4 r;
  float t;
  t = y.x * sc + sh; r.x = xv.x + fmaxf(t, 0.f) + a * fminf(t, 0.f);
  t = y.y * sc + sh; r.y = xv.y + fmaxf(t, 0.f) + a * fminf(t, 0.f);
  t = y.z * sc + sh; r.z = xv.z + fmaxf(t, 0.f) + a * fminf(t, 0.f);
  t = y.w * sc + sh; r.w = xv.w + fmaxf(t, 0.f) + a * fminf(t, 0.f);
  *(float4*)&out[idx] = r;
}

extern "C" void kernel_launch(void* const* d_in, const int* in_sizes, int n_in,
                              void* d_out, int out_size, void* d_ws, size_t ws_size,
                              hipStream_t stream) {
  const float* x     = (const float*)d_in[0];
  const float* camw  = (const float*)d_in[1];
  const float* camb  = (const float*)d_in[2];
  const float* gw1   = (const float*)d_in[3];
  const float* ga    = (const float*)d_in[4];
  const float* gw2   = (const float*)d_in[5];
  const float* fw    = (const float*)d_in[6];
  const float* fb    = (const float*)d_in[7];
  const float* ra    = (const float*)d_in[8];
  const float* qw    = (const float*)d_in[9];
  const float* qb    = (const float*)d_in[10];
  const float* kw    = (const float*)d_in[11];
  const float* kb    = (const float*)d_in[12];
  const float* vw    = (const float*)d_in[13];
  const float* vb    = (const float*)d_in[14];
  const float* ow    = (const float*)d_in[15];
  const float* gamma = (const float*)d_in[16];
  const float* beta  = (const float*)d_in[17];
  const float* oa    = (const float*)d_in[18];
  float* out = (float*)d_out;
  float* ws = (float*)d_ws;

  // workspace layout (float units)
  float* cam   = ws;                   // 1,245,184
  float* bconf = cam + 1245184;        // 2,048
  float* pconf = bconf + 2048;         // 1,245,184
  float* locl  = pconf + 1245184;      // 622,592
  float* locl2 = locl + 622592;        // 622,592
  float* keyo  = locl2 + 622592;       // 311,296
  float* valo  = keyo + 311296;        // 38,912
  float* sums  = valo + 38912;         // 512
  float* sumsq = sums + 512;           // 512
  float* scale = sumsq + 512;          // 512
  float* shift = scale + 512;          // 512
  u16* qwbf = (u16*)(shift + 512);     // 131,072 u16
  u16* owbf = qwbf + 131072;           // 131,072 u16
  u16* xt   = owbf + 131072;           // 33,554,432 u16 (64 MB)
  u16* obuf = xt;                      // overlay: attention runs after qproj consumed xt
  u16* qbuf = xt + 33554432;           // 16,777,216 u16 (32 MB)
  // total ~112 MB

  zero_kernel<<<4, 256, 0, stream>>>(sums);
  w2bf_kernel<<<512, 256, 0, stream>>>(qw, qwbf);
  w2bf_kernel<<<512, 256, 0, stream>>>(ow, owbf);
  xpose_kernel<<<8192, 256, 0, stream>>>(x, xt);
  cam_kernel<<<512, 128, 0, stream>>>(x, camw, camb, cam);
  cls_kernel<<<1216, 256, 0, stream>>>(cam, bconf);
  softmax_kernel<<<1216, 256, 0, stream>>>(cam, pconf);
  local_kernel<<<128, 256, 0, stream>>>(x, pconf, bconf, locl);
  gcn_key_kernel<<<1216, 256, 0, stream>>>(locl, gw1, ga, gw2, kw, kb, locl2, keyo);
  glob_val_kernel<<<152, 256, 0, stream>>>(locl2, fw, fb, ra, vw, vb, valo);
  // q projection: q[b][hw][i] (bf16) = xt[b][hw][:] . qw[i][:] + qb
  gemm_kernel<512, 256, false, true, true>
      <<<dim3(128, 8), 256, 0, stream>>>(xt, qwbf, qb, qbuf);
  attn2_kernel<<<512, 256, 0, stream>>>(qbuf, keyo, valo, obuf);
  // y[b][c][hw] (fp32, in d_out) = obuf[b][hw][:] . ow[c][:]
  gemm_kernel<256, 512, true, false, false>
      <<<dim3(256, 8), 256, 0, stream>>>(obuf, owbf, nullptr, out);
  bnstats_kernel<<<2048, 256, 0, stream>>>(out, sums, sumsq);
  bnfinal_kernel<<<1, 512, 0, stream>>>(sums, sumsq, gamma, beta, scale, shift);
  final_kernel<<<32768, 256, 0, stream>>>(x, scale, shift, oa, out);
}

// Round 3
// 576.216 us; speedup vs baseline: 5.2302x; 1.5394x over previous
//
#include <hip/hip_runtime.h>
#include <cstdint>
#include <cstddef>

#define B_ 8
#define C_ 512
#define H_ 64
#define W_ 128
#define HW_ 8192
#define K_ 19
#define N_ 8
#define P_ 1024
#define CI_ 256

typedef unsigned short u16;
typedef unsigned int u32;
typedef __attribute__((ext_vector_type(8))) short bf16x8;   // 8 bf16 (4 VGPRs)
typedef __attribute__((ext_vector_type(4))) float f32x4;    // 4 fp32 acc

__device__ __forceinline__ u16 f2bf(float f) {
  u32 u = __float_as_uint(f);
  u32 r = (u + 0x7FFFu + ((u >> 16) & 1u)) >> 16;
  return (u16)r;
}
__device__ __forceinline__ float bf2f(u16 h) {
  return __uint_as_float(((u32)h) << 16);
}

// ---------------- block reductions (256 threads = 4 waves) ----------------
__device__ __forceinline__ float blockSum256(float v, float* red4) {
#pragma unroll
  for (int o = 32; o > 0; o >>= 1) v += __shfl_down(v, o, 64);
  __syncthreads();
  if ((threadIdx.x & 63) == 0) red4[threadIdx.x >> 6] = v;
  __syncthreads();
  return red4[0] + red4[1] + red4[2] + red4[3];
}

__device__ __forceinline__ float blockMax256(float v, float* red4) {
#pragma unroll
  for (int o = 32; o > 0; o >>= 1) v = fmaxf(v, __shfl_down(v, o, 64));
  __syncthreads();
  if ((threadIdx.x & 63) == 0) red4[threadIdx.x >> 6] = v;
  __syncthreads();
  return fmaxf(fmaxf(red4[0], red4[1]), fmaxf(red4[2], red4[3]));
}

__global__ void zero_kernel(float* __restrict__ p) {
  p[blockIdx.x * 256 + threadIdx.x] = 0.f;
}

// ---------------- convert weights fp32 -> bf16 ----------------
__global__ __launch_bounds__(256) void w2bf_kernel(const float* __restrict__ a,
                                                   u16* __restrict__ o) {
  int i = blockIdx.x * 256 + threadIdx.x;
  o[i] = f2bf(a[i]);
}

// camw [19][512] -> bf16 [32][512], zero-padded rows 19..31
__global__ __launch_bounds__(256) void camw2bf_kernel(const float* __restrict__ a,
                                                      u16* __restrict__ o) {
  int i = blockIdx.x * 256 + threadIdx.x;  // 0..16383
  o[i] = (i < K_ * C_) ? f2bf(a[i]) : (u16)0;
}

// ---------------- transpose x [b,c,hw] -> xt bf16 [b,hw,c] ----------------
__global__ __launch_bounds__(256) void xpose_kernel(const float* __restrict__ x,
                                                    u16* __restrict__ xt) {
  __shared__ float tile[64][65];
  int bid = blockIdx.x;
  int hw0 = (bid & 127) << 6;
  int c0 = ((bid >> 7) & 7) << 6;
  int b = bid >> 10;
  int tid = threadIdx.x;
  int r = tid >> 4;             // 0..15
  int col4 = (tid & 15) << 2;   // 0..60
  const float* xb = x + ((size_t)b * C_ + c0) * HW_ + hw0;
#pragma unroll
  for (int it = 0; it < 4; it++) {
    int rr = r + it * 16;  // c-row
    float4 v = *(const float4*)&xb[(size_t)rr * HW_ + col4];
    tile[rr][col4 + 0] = v.x;
    tile[rr][col4 + 1] = v.y;
    tile[rr][col4 + 2] = v.z;
    tile[rr][col4 + 3] = v.w;
  }
  __syncthreads();
  u16* xo = xt + ((size_t)b * HW_ + hw0) * C_ + c0;
#pragma unroll
  for (int it = 0; it < 4; it++) {
    int hwr = r + it * 16;  // hw-row
    ushort4 o;
    o.x = f2bf(tile[col4 + 0][hwr]);
    o.y = f2bf(tile[col4 + 1][hwr]);
    o.z = f2bf(tile[col4 + 2][hwr]);
    o.w = f2bf(tile[col4 + 3][hwr]);
    *(ushort4*)&xo[(size_t)hwr * C_ + col4] = o;
  }
}

// ---------------- cam via MFMA: cam[b,k,hw] = xt[b,hw,:].camw[k,:] + camb[k] ----------------
// tile M=128(hw) x N=32(k); grid (64, 8)
__global__ __launch_bounds__(256) void gemm_cam_kernel(const u16* __restrict__ A,
                                                       const u16* __restrict__ Bw,
                                                       const float* __restrict__ bias,
                                                       float* __restrict__ cam) {
  __shared__ u16 As[128 * 72];
  __shared__ u16 Bs[32 * 72];
  int b = blockIdx.y;
  int m0 = blockIdx.x * 128;
  int tid = threadIdx.x;
  int wave = tid >> 6, lane = tid & 63;
  int wm = wave * 32;
  int quad = lane >> 4, l16 = lane & 15;
  const u16* Ab = A + (size_t)b * HW_ * C_ + (size_t)m0 * C_;
  f32x4 acc[2][2] = {};
  int sr = tid >> 3;
  int sk = (tid & 7) * 8;
  for (int k0 = 0; k0 < C_; k0 += 64) {
    __syncthreads();
#pragma unroll
    for (int it = 0; it < 4; it++) {
      int r = sr + it * 32;
      *(uint4*)&As[r * 72 + sk] = *(const uint4*)&Ab[(size_t)r * C_ + k0 + sk];
    }
    { int r = tid >> 3;  // 0..31
      *(uint4*)&Bs[r * 72 + sk] = *(const uint4*)&Bw[(size_t)r * C_ + k0 + sk]; }
    __syncthreads();
#pragma unroll
    for (int kk = 0; kk < 2; kk++) {
      bf16x8 af[2], bfv[2];
#pragma unroll
      for (int t = 0; t < 2; t++) {
        af[t] = *(const bf16x8*)&As[(wm + t * 16 + l16) * 72 + kk * 32 + quad * 8];
        bfv[t] = *(const bf16x8*)&Bs[(t * 16 + l16) * 72 + kk * 32 + quad * 8];
      }
#pragma unroll
      for (int tm = 0; tm < 2; tm++)
#pragma unroll
        for (int tn = 0; tn < 2; tn++)
          acc[tm][tn] = __builtin_amdgcn_mfma_f32_16x16x32_bf16(af[tm], bfv[tn], acc[tm][tn], 0, 0, 0);
    }
  }
  float* C = cam + (size_t)b * K_ * HW_;
#pragma unroll
  for (int tm = 0; tm < 2; tm++) {
    int mm = m0 + wm + tm * 16 + quad * 4;
#pragma unroll
    for (int tn = 0; tn < 2; tn++) {
      int nn = tn * 16 + l16;
      if (nn < K_) {
        float bv = bias[nn];
        f32x4 v = acc[tm][tn];
        v[0] += bv; v[1] += bv; v[2] += bv; v[3] += bv;
        *(f32x4*)&C[(size_t)nn * HW_ + mm] = v;
      }
    }
  }
}

// ---------------- fused cls+softmax: bconf + pconf from cam patch ----------------
__global__ __launch_bounds__(256) void softcls_kernel(const float* __restrict__ cam,
                                                      float* __restrict__ bconf,
                                                      float* __restrict__ pconf) {
  __shared__ float red4[4];
  int bid = blockIdx.x;
  int k = bid % 19;
  int n = (bid / 19) & 7;
  int b = bid / 152;
  int bh = n >> 2, bw = n & 3;
  const float* base = cam + ((size_t)b * K_ + k) * HW_ + (bh * 32) * W_ + bw * 32;
  float v[4];
  float s = 0.f, mx = -1e30f;
#pragma unroll
  for (int j = 0; j < 4; j++) {
    int p = threadIdx.x + j * 256;
    v[j] = base[(p >> 5) * W_ + (p & 31)];
    s += v[j];
    mx = fmaxf(mx, v[j]);
  }
  float tot = blockSum256(s, red4);
  if (threadIdx.x == 0) {
    float m = tot * (1.f / 1024.f);
    bconf[bid] = 1.f / (1.f + __expf(-m));
  }
  mx = blockMax256(mx, red4);
  float e[4];
  float se = 0.f;
#pragma unroll
  for (int j = 0; j < 4; j++) { e[j] = __expf(v[j] - mx); se += e[j]; }
  se = blockSum256(se, red4);
  float inv = 1.f / se;
  float* outp = pconf + (size_t)bid * P_;
#pragma unroll
  for (int j = 0; j < 4; j++) outp[threadIdx.x + j * 256] = e[j] * inv;
}

// ---------------- local partial: sum over 256-p chunk ----------------
// grid 512: pq = bid&3, half=(bid>>2)&1, n=(bid>>3)&7, b=bid>>6
__global__ __launch_bounds__(256) void local_part_kernel(const u16* __restrict__ xt,
                                                         const float* __restrict__ pconf,
                                                         float* __restrict__ part) {
  __shared__ float pcl[19 * 256];
  int bid = blockIdx.x;
  int pq = bid & 3;
  int half = (bid >> 2) & 1;
  int n = (bid >> 3) & 7;
  int b = bid >> 6;
  int tid = threadIdx.x;
  int c = half * 256 + tid;
  int bh = n >> 2, bw = n & 3;
  const float* pcb = pconf + (size_t)((b * N_ + n) * K_) * P_ + pq * 256;
  for (int e = tid; e < 19 * 256; e += 256) {
    int k = e >> 8, pl = e & 255;
    pcl[e] = pcb[(size_t)k * P_ + pl];
  }
  __syncthreads();
  float acc[K_];
#pragma unroll
  for (int k = 0; k < K_; k++) acc[k] = 0.f;
  const u16* xb = xt + (size_t)b * HW_ * C_ + c;
#pragma unroll 4
  for (int pl = 0; pl < 256; pl++) {
    int p = pq * 256 + pl;
    int hw = (bh * 32 + (p >> 5)) * W_ + bw * 32 + (p & 31);
    float xv = bf2f(xb[(size_t)hw * C_]);
#pragma unroll
    for (int k = 0; k < K_; k++) acc[k] += pcl[k * 256 + pl] * xv;
  }
  int row = (b * N_ + n) * K_;
  float* pp = part + ((size_t)pq * 1216 + row) * C_ + c;
#pragma unroll
  for (int k = 0; k < K_; k++) pp[(size_t)k * C_] = acc[k];
}

// ---------------- local reduce: locl = bconf * (p0+p1+p2+p3) ----------------
__global__ __launch_bounds__(256) void local_reduce_kernel(const float* __restrict__ part,
                                                           const float* __restrict__ bconf,
                                                           float* __restrict__ locl) {
  int idx = blockIdx.x * 256 + threadIdx.x;  // 0..622591
  int r = idx >> 9;
  float s = part[idx] + part[idx + 1216 * 512] + part[idx + 2 * 1216 * 512] + part[idx + 3 * 1216 * 512];
  locl[idx] = s * bconf[r];
}

// ---------------- t = prelu(gcn conv over bins + residual) -> bf16 rows ----------------
// grid 304: half=bid&1, k=(bid>>1)%19, b=(bid>>1)/19
__global__ __launch_bounds__(256) void t_kernel(const float* __restrict__ locl,
                                                const float* __restrict__ gw1,
                                                const float* __restrict__ ga,
                                                u16* __restrict__ tbuf) {
  __shared__ float gw1l[64];
  __shared__ float gal[8];
  int tid = threadIdx.x;
  if (tid < 64) gw1l[tid] = gw1[tid];
  if (tid < 8) gal[tid] = ga[tid];
  __syncthreads();
  int bid = blockIdx.x;
  int half = bid & 1;
  int rem = bid >> 1;
  int k = rem % 19;
  int b = rem / 19;
  int c = half * 256 + tid;
  const float* lb = locl + ((size_t)(b * N_) * K_ + k) * C_ + c;
  float lm[8];
#pragma unroll
  for (int m = 0; m < 8; m++) lm[m] = lb[(size_t)m * K_ * C_];
#pragma unroll
  for (int n = 0; n < 8; n++) {
    float v = lm[n];
#pragma unroll
    for (int m = 0; m < 8; m++) v += gw1l[n * 8 + m] * lm[m];
    float t = fmaxf(v, 0.f) + gal[n] * fminf(v, 0.f);
    tbuf[((size_t)((b * N_ + n) * K_ + k)) * C_ + c] = f2bf(t);
  }
}

// ---------------- small GEMM (M=1280 padded): C = A.Bw^T (+bias), dual fp32/bf16 out --------
template <int KDIM, int NDIM, bool BIAS>
__global__ __launch_bounds__(256) void gemm_small_kernel(const u16* __restrict__ A,
                                                         const u16* __restrict__ Bw,
                                                         const float* __restrict__ bias,
                                                         float* __restrict__ f32out,
                                                         u16* __restrict__ bf16out) {
  __shared__ u16 As[128 * 72];
  __shared__ u16 Bs[128 * 72];
  constexpr int NT = NDIM / 128;
  int m0 = (blockIdx.x / NT) * 128;
  int n0 = (blockIdx.x % NT) * 128;
  int tid = threadIdx.x;
  int wave = tid >> 6, lane = tid & 63;
  int wm = (wave >> 1) * 64, wn = (wave & 1) * 64;
  int quad = lane >> 4, l16 = lane & 15;
  const u16* Ab = A + (size_t)m0 * KDIM;
  const u16* Bb = Bw + (size_t)n0 * KDIM;
  f32x4 acc[4][4] = {};
  int sr = tid >> 3;
  int sk = (tid & 7) * 8;
  for (int k0 = 0; k0 < KDIM; k0 += 64) {
    __syncthreads();
#pragma unroll
    for (int it = 0; it < 4; it++) {
      int r = sr + it * 32;
      *(uint4*)&As[r * 72 + sk] = *(const uint4*)&Ab[(size_t)r * KDIM + k0 + sk];
      *(uint4*)&Bs[r * 72 + sk] = *(const uint4*)&Bb[(size_t)r * KDIM + k0 + sk];
    }
    __syncthreads();
#pragma unroll
    for (int kk = 0; kk < 2; kk++) {
      bf16x8 af[4], bfv[4];
#pragma unroll
      for (int t = 0; t < 4; t++) {
        af[t] = *(const bf16x8*)&As[(wm + t * 16 + l16) * 72 + kk * 32 + quad * 8];
        bfv[t] = *(const bf16x8*)&Bs[(wn + t * 16 + l16) * 72 + kk * 32 + quad * 8];
      }
#pragma unroll
      for (int tm = 0; tm < 4; tm++)
#pragma unroll
        for (int tn = 0; tn < 4; tn++)
          acc[tm][tn] = __builtin_amdgcn_mfma_f32_16x16x32_bf16(af[tm], bfv[tn], acc[tm][tn], 0, 0, 0);
    }
  }
  float bv[4];
#pragma unroll
  for (int tn = 0; tn < 4; tn++)
    bv[tn] = BIAS ? bias[n0 + wn + tn * 16 + l16] : 0.f;
#pragma unroll
  for (int tm = 0; tm < 4; tm++) {
    int mm = m0 + wm + tm * 16 + quad * 4;
#pragma unroll
    for (int tn = 0; tn < 4; tn++) {
      int nn = n0 + wn + tn * 16 + l16;
#pragma unroll
      for (int reg = 0; reg < 4; reg++) {
        float v = acc[tm][tn][reg] + bv[tn];
        if (f32out) f32out[(size_t)(mm + reg) * NDIM + nn] = v;
        if (bf16out) bf16out[(size_t)(mm + reg) * NDIM + nn] = f2bf(v);
      }
    }
  }
}

// ---------------- 6: glob + val ----------------
__global__ __launch_bounds__(256) void glob_val_kernel(const float* __restrict__ locl2,
                                                       const float* __restrict__ fw,
                                                       const float* __restrict__ fb,
                                                       const float* __restrict__ ra,
                                                       const float* __restrict__ vw,
                                                       const float* __restrict__ vb,
                                                       float* __restrict__ valo) {
  __shared__ __align__(16) float gl[512];
  int bid = blockIdx.x;
  int k = bid % 19;
  int b = bid / 19;
  int tid = threadIdx.x;
  float fwr[8];
#pragma unroll
  for (int m = 0; m < 8; m++) fwr[m] = fw[m];
  float fbv = fb[0], rav = ra[0];
  const float* lb = locl2 + ((size_t)(b * N_) * K_ + k) * C_;
  for (int c = tid; c < C_; c += 256) {
    float v = fbv;
#pragma unroll
    for (int m = 0; m < 8; m++) v += fwr[m] * lb[(size_t)m * K_ * C_ + c];
    gl[c] = fmaxf(v, 0.f) + rav * fminf(v, 0.f);
  }
  __syncthreads();
  int i = tid;
  const float* wr = vw + (size_t)i * C_;
  float s = vb[i];
  for (int c4 = 0; c4 < C_; c4 += 4) {
    float4 wv = *(const float4*)&wr[c4];
    float4 tv = *(const float4*)&gl[c4];
    s += wv.x * tv.x + wv.y * tv.y + wv.z * tv.z + wv.w * tv.w;
  }
  valo[(size_t)bid * CI_ + i] = s;
}

// ---------------- big MFMA GEMM (per-batch 8192 rows) ----------------
// TRANS_OUT: write fp32 C[b][n][m]; else C[b][m][n] (bf16 if OUTBF16). BNSTAT: per-channel sum/sumsq.
template <int KDIM, int NDIM, bool TRANS_OUT, bool BIAS, bool OUTBF16, bool BNSTAT>
__global__ __launch_bounds__(256) void gemm_big_kernel(const u16* __restrict__ A,
                                                       const u16* __restrict__ Bw,
                                                       const float* __restrict__ bias,
                                                       void* __restrict__ Cout,
                                                       float* __restrict__ sums,
                                                       float* __restrict__ sumsq) {
  __shared__ u16 As[128 * 72];
  __shared__ u16 Bs[128 * 72];
  constexpr int NT = NDIM / 128;
  int b = blockIdx.y;
  int m0 = (blockIdx.x / NT) * 128;
  int n0 = (blockIdx.x % NT) * 128;
  int tid = threadIdx.x;
  int wave = tid >> 6, lane = tid & 63;
  int wm = (wave >> 1) * 64, wn = (wave & 1) * 64;
  int quad = lane >> 4, l16 = lane & 15;
  const u16* Ab = A + (size_t)b * 8192 * KDIM + (size_t)m0 * KDIM;
  const u16* Bb = Bw + (size_t)n0 * KDIM;
  f32x4 acc[4][4] = {};
  int sr = tid >> 3;
  int sk = (tid & 7) * 8;
  for (int k0 = 0; k0 < KDIM; k0 += 64) {
    __syncthreads();
#pragma unroll
    for (int it = 0; it < 4; it++) {
      int r = sr + it * 32;
      *(uint4*)&As[r * 72 + sk] = *(const uint4*)&Ab[(size_t)r * KDIM + k0 + sk];
      *(uint4*)&Bs[r * 72 + sk] = *(const uint4*)&Bb[(size_t)r * KDIM + k0 + sk];
    }
    __syncthreads();
#pragma unroll
    for (int kk = 0; kk < 2; kk++) {
      bf16x8 af[4], bfv[4];
#pragma unroll
      for (int t = 0; t < 4; t++) {
        af[t] = *(const bf16x8*)&As[(wm + t * 16 + l16) * 72 + kk * 32 + quad * 8];
        bfv[t] = *(const bf16x8*)&Bs[(wn + t * 16 + l16) * 72 + kk * 32 + quad * 8];
      }
#pragma unroll
      for (int tm = 0; tm < 4; tm++)
#pragma unroll
        for (int tn = 0; tn < 4; tn++)
          acc[tm][tn] = __builtin_amdgcn_mfma_f32_16x16x32_bf16(af[tm], bfv[tn], acc[tm][tn], 0, 0, 0);
    }
  }
  if constexpr (!TRANS_OUT) {
    float bv[4];
#pragma unroll
    for (int tn = 0; tn < 4; tn++)
      bv[tn] = BIAS ? bias[n0 + wn + tn * 16 + l16] : 0.f;
#pragma unroll
    for (int tm = 0; tm < 4; tm++) {
      int mm = m0 + wm + tm * 16 + quad * 4;
#pragma unroll
      for (int tn = 0; tn < 4; tn++) {
        int nn = n0 + wn + tn * 16 + l16;
        if constexpr (OUTBF16) {
          u16* C = (u16*)Cout + (size_t)b * 8192 * NDIM;
#pragma unroll
          for (int reg = 0; reg < 4; reg++)
            C[(size_t)(mm + reg) * NDIM + nn] = f2bf(acc[tm][tn][reg] + bv[tn]);
        } else {
          float* C = (float*)Cout + (size_t)b * 8192 * NDIM;
#pragma unroll
          for (int reg = 0; reg < 4; reg++)
            C[(size_t)(mm + reg) * NDIM + nn] = acc[tm][tn][reg] + bv[tn];
        }
      }
    }
  } else {
    float* C = (float*)Cout + (size_t)b * NDIM * 8192;
#pragma unroll
    for (int tm = 0; tm < 4; tm++) {
      int mm = m0 + wm + tm * 16 + quad * 4;
#pragma unroll
      for (int tn = 0; tn < 4; tn++) {
        int nn = n0 + wn + tn * 16 + l16;
        *(f32x4*)&C[(size_t)nn * 8192 + mm] = acc[tm][tn];
      }
    }
    if constexpr (BNSTAT) {
#pragma unroll
      for (int tn = 0; tn < 4; tn++) {
        int nn = n0 + wn + tn * 16 + l16;
        float s = 0.f, q = 0.f;
#pragma unroll
        for (int tm = 0; tm < 4; tm++)
#pragma unroll
          for (int reg = 0; reg < 4; reg++) {
            float v = acc[tm][tn][reg];
            s += v;
            q += v * v;
          }
        s += __shfl_xor(s, 16, 64); q += __shfl_xor(q, 16, 64);
        s += __shfl_xor(s, 32, 64); q += __shfl_xor(q, 32, 64);
        if (quad == 0) {
          atomicAdd(&sums[nn], s);
          atomicAdd(&sumsq[nn], q);
        }
      }
    }
  }
}

// ---------------- attention ----------------
__global__ __launch_bounds__(256) void attn2_kernel(const u16* __restrict__ q,
                                                    const float* __restrict__ keyo,
                                                    const float* __restrict__ valo,
                                                    u16* __restrict__ obuf) {
  __shared__ float keyl[19 * 256];
  __shared__ float vall[19 * 256];
  __shared__ float aff[128 * 20];
  int bid = blockIdx.x;
  int rg = bid & 7;
  int n = (bid >> 3) & 7;
  int b = bid >> 6;
  int bh = n >> 2, bw = n & 3;
  int tid = threadIdx.x;
  const float* ksrc = keyo + (size_t)((b * 8 + n) * 19) * 256;
  for (int e = tid; e < 19 * 256; e += 256) keyl[e] = ksrc[e];
  __syncthreads();
  if (tid < 128) {
    int r = rg * 4 + (tid >> 5);
    int wc = tid & 31;
    int hw = (bh * 32 + r) * W_ + bw * 32 + wc;
    const u16* qr = q + ((size_t)b * HW_ + hw) * 256;
    float acc[19];
#pragma unroll
    for (int k = 0; k < 19; k++) acc[k] = 0.f;
    for (int i0 = 0; i0 < 256; i0 += 8) {
      uint4 v = *(const uint4*)&qr[i0];
      float f0 = __uint_as_float((v.x & 0xFFFFu) << 16);
      float f1 = __uint_as_float(v.x & 0xFFFF0000u);
      float f2 = __uint_as_float((v.y & 0xFFFFu) << 16);
      float f3 = __uint_as_float(v.y & 0xFFFF0000u);
      float f4 = __uint_as_float((v.z & 0xFFFFu) << 16);
      float f5 = __uint_as_float(v.z & 0xFFFF0000u);
      float f6 = __uint_as_float((v.w & 0xFFFFu) << 16);
      float f7 = __uint_as_float(v.w & 0xFFFF0000u);
#pragma unroll
      for (int k = 0; k < 19; k++) {
        const float* kr = &keyl[k * 256 + i0];
        acc[k] += f0 * kr[0] + f1 * kr[1] + f2 * kr[2] + f3 * kr[3] +
                  f4 * kr[4] + f5 * kr[5] + f6 * kr[6] + f7 * kr[7];
      }
    }
    float mx = -1e30f;
#pragma unroll
    for (int k = 0; k < 19; k++) mx = fmaxf(mx, acc[k]);
    float se = 0.f;
#pragma unroll
    for (int k = 0; k < 19; k++) { acc[k] = __expf(acc[k] - mx); se += acc[k]; }
    float inv = 1.f / se;
#pragma unroll
    for (int k = 0; k < 19; k++) aff[tid * 20 + k] = acc[k] * inv;
  } else {
    const float* vsrc = valo + (size_t)b * 19 * 256;
    for (int e = tid - 128; e < 19 * 256; e += 128) vall[e] = vsrc[e];
  }
  __syncthreads();
  int px = tid & 127;
  int ih = (tid >> 7) * 128;
  int r3 = rg * 4 + (px >> 5);
  int wc3 = px & 31;
  int hw3 = (bh * 32 + r3) * W_ + bw * 32 + wc3;
  float av[19];
#pragma unroll
  for (int k = 0; k < 19; k++) av[k] = aff[px * 20 + k];
  u16* ob = obuf + ((size_t)b * HW_ + hw3) * 256 + ih;
  for (int i0 = 0; i0 < 128; i0 += 16) {
    float o16[16];
#pragma unroll
    for (int j = 0; j < 16; j++) o16[j] = 0.f;
#pragma unroll
    for (int k = 0; k < 19; k++) {
      float a = av[k];
      const float* vr = &vall[k * 256 + ih + i0];
#pragma unroll
      for (int j = 0; j < 16; j++) o16[j] += a * vr[j];
    }
    uint4 w0, w1;
    w0.x = (u32)f2bf(o16[0]) | ((u32)f2bf(o16[1]) << 16);
    w0.y = (u32)f2bf(o16[2]) | ((u32)f2bf(o16[3]) << 16);
    w0.z = (u32)f2bf(o16[4]) | ((u32)f2bf(o16[5]) << 16);
    w0.w = (u32)f2bf(o16[6]) | ((u32)f2bf(o16[7]) << 16);
    w1.x = (u32)f2bf(o16[8]) | ((u32)f2bf(o16[9]) << 16);
    w1.y = (u32)f2bf(o16[10]) | ((u32)f2bf(o16[11]) << 16);
    w1.z = (u32)f2bf(o16[12]) | ((u32)f2bf(o16[13]) << 16);
    w1.w = (u32)f2bf(o16[14]) | ((u32)f2bf(o16[15]) << 16);
    *(uint4*)&ob[i0] = w0;
    *(uint4*)&ob[i0 + 8] = w1;
  }
}

__global__ __launch_bounds__(512) void bnfinal_kernel(const float* __restrict__ sums,
                                                      const float* __restrict__ sumsq,
                                                      const float* __restrict__ gamma,
                                                      const float* __restrict__ beta,
                                                      float* __restrict__ scale,
                                                      float* __restrict__ shift) {
  int c = threadIdx.x;
  const float inv_cnt = 1.f / 65536.f;
  float mu = sums[c] * inv_cnt;
  float var = sumsq[c] * inv_cnt - mu * mu;
  float iv = rsqrtf(var + 1e-5f);
  float sc = gamma[c] * iv;
  scale[c] = sc;
  shift[c] = beta[c] - mu * sc;
}

__global__ __launch_bounds__(256) void final_kernel(const float* __restrict__ x,
                                                    const float* __restrict__ scale,
                                                    const float* __restrict__ shift,
                                                    const float* __restrict__ oa,
                                                    float* __restrict__ out) {
  size_t idx = ((size_t)blockIdx.x * 256 + threadIdx.x) * 4;
  int c = (int)((idx >> 13) & 511);
  float sc = scale[c], sh = shift[c], a = oa[c];
  float4 y = *(float4*)&out[idx];
  float4 xv = *(const float4*)&x[idx];
  float4 r;
  float t;
  t = y.x * sc + sh; r.x = xv.x + fmaxf(t, 0.f) + a * fminf(t, 0.f);
  t = y.y * sc + sh; r.y = xv.y + fmaxf(t, 0.f) + a * fminf(t, 0.f);
  t = y.z * sc + sh; r.z = xv.z + fmaxf(t, 0.f) + a * fminf(t, 0.f);
  t = y.w * sc + sh; r.w = xv.w + fmaxf(t, 0.f) + a * fminf(t, 0.f);
  *(float4*)&out[idx] = r;
}

extern "C" void kernel_launch(void* const* d_in, const int* in_sizes, int n_in,
                              void* d_out, int out_size, void* d_ws, size_t ws_size,
                              hipStream_t stream) {
  const float* x     = (const float*)d_in[0];
  const float* camw  = (const float*)d_in[1];
  const float* camb  = (const float*)d_in[2];
  const float* gw1   = (const float*)d_in[3];
  const float* ga    = (const float*)d_in[4];
  const float* gw2   = (const float*)d_in[5];
  const float* fw    = (const float*)d_in[6];
  const float* fb    = (const float*)d_in[7];
  const float* ra    = (const float*)d_in[8];
  const float* qw    = (const float*)d_in[9];
  const float* qb    = (const float*)d_in[10];
  const float* kw    = (const float*)d_in[11];
  const float* kb    = (const float*)d_in[12];
  const float* vw    = (const float*)d_in[13];
  const float* vb    = (const float*)d_in[14];
  const float* ow    = (const float*)d_in[15];
  const float* gamma = (const float*)d_in[16];
  const float* beta  = (const float*)d_in[17];
  const float* oa    = (const float*)d_in[18];
  float* out = (float*)d_out;
  float* ws = (float*)d_ws;

  // ---- workspace layout (float units) ----
  float* cam    = ws;                    // 1,245,184
  float* bconf  = cam + 1245184;         // 2,048 pad
  float* pconf  = bconf + 2048;          // 1,245,184
  float* locl   = pconf + 1245184;       // 622,592
  float* locl2f = locl + 622592;         // 1280*512 = 655,360
  float* keyo   = locl2f + 655360;       // 1280*256 = 327,680
  float* valo   = keyo + 327680;         // 38,912
  float* sums   = valo + 38912;          // 512
  float* sumsq  = sums + 512;            // 512
  float* scale  = sumsq + 512;           // 512
  float* shift  = scale + 512;           // 512
  u16* qwbf   = (u16*)(shift + 512);     // 131,072
  u16* owbf   = qwbf + 131072;           // 131,072
  u16* kwbf   = owbf + 131072;           // 131,072
  u16* gw2bf  = kwbf + 131072;           // 262,144
  u16* camwbf = gw2bf + 262144;          // 16,384 (32x512)
  u16* tbuf   = camwbf + 16384;          // 1280*512 = 655,360
  u16* l2bf   = tbuf + 655360;           // 1280*512 = 655,360
  u16* xt     = l2bf + 655360;           // 33,554,432 (64 MB)
  u16* obuf   = xt;                      // overlay: all xt readers precede attn2
  u16* qbuf   = xt + 33554432;           // 16,777,216 (32 MB)
  float* part = (float*)qbuf;            // overlay: 4*1216*512 = 2,490,368 f, consumed before qproj

  zero_kernel<<<4, 256, 0, stream>>>(sums);                       // sums+sumsq+scale+shift
  w2bf_kernel<<<512, 256, 0, stream>>>(qw, qwbf);
  w2bf_kernel<<<512, 256, 0, stream>>>(ow, owbf);
  w2bf_kernel<<<512, 256, 0, stream>>>(kw, kwbf);
  w2bf_kernel<<<1024, 256, 0, stream>>>(gw2, gw2bf);
  camw2bf_kernel<<<64, 256, 0, stream>>>(camw, camwbf);
  zero_kernel<<<64, 256, 0, stream>>>((float*)(tbuf + 1216 * 512));  // zero tbuf pad rows

  xpose_kernel<<<8192, 256, 0, stream>>>(x, xt);
  gemm_cam_kernel<<<dim3(64, 8), 256, 0, stream>>>(xt, camwbf, camb, cam);
  softcls_kernel<<<1216, 256, 0, stream>>>(cam, bconf, pconf);
  local_part_kernel<<<512, 256, 0, stream>>>(xt, pconf, part);
  local_reduce_kernel<<<2432, 256, 0, stream>>>(part, bconf, locl);
  t_kernel<<<304, 256, 0, stream>>>(locl, gw1, ga, tbuf);
  gemm_small_kernel<512, 512, false>
      <<<40, 256, 0, stream>>>(tbuf, gw2bf, nullptr, locl2f, l2bf);
  gemm_small_kernel<512, 256, true>
      <<<20, 256, 0, stream>>>(l2bf, kwbf, kb, keyo, nullptr);
  glob_val_kernel<<<152, 256, 0, stream>>>(locl2f, fw, fb, ra, vw, vb, valo);
  gemm_big_kernel<512, 256, false, true, true, false>
      <<<dim3(128, 8), 256, 0, stream>>>(xt, qwbf, qb, qbuf, nullptr, nullptr);
  attn2_kernel<<<512, 256, 0, stream>>>(qbuf, keyo, valo, obuf);
  gemm_big_kernel<256, 512, true, false, false, true>
      <<<dim3(256, 8), 256, 0, stream>>>(obuf, owbf, nullptr, out, sums, sumsq);
  bnfinal_kernel<<<1, 512, 0, stream>>>(sums, sumsq, gamma, beta, scale, shift);
  final_kernel<<<32768, 256, 0, stream>>>(x, scale, shift, oa, out);
}